// Round 15
// baseline (847.245 us; speedup 1.0000x reference)
//
#include <hip/hip_runtime.h>

typedef unsigned int u32;
typedef unsigned char u8;

#define NN 100000
#define NE 3200000
#define NB 256
#define FTD 41
#define DIM 32
#define NBK 782      // ceil(NN/128)
#define SCHUNK 8000  // edges per k_bscatter block; 400*8000 == NE

typedef __fp16 fp16x2 __attribute__((ext_vector_type(2)));

__device__ __forceinline__ float h16f(u32 bits) {
  union { unsigned short s; _Float16 h; } c;
  c.s = (unsigned short)bits;
  return (float)c.h;
}
__device__ __forceinline__ u32 pk2(float a, float b) {
  union { fp16x2 h; u32 u; } c;
  c.h = __builtin_amdgcn_cvt_pkrtz(a, b);
  return c.u;
}

// fp8 e4m3fn encode (software, OCP-compatible; RNE via f16 path)
__device__ __forceinline__ u8 f8enc(float v) {
  union { _Float16 h; unsigned short u; } cv;
  cv.h = (_Float16)(v * 0.00390625f);  // v / 256
  u32 h = cv.u;
  u32 mag = h & 0x7fffu;
  u32 base = mag >> 7;
  u32 low = mag & 0x7fu;
  base += (low > 0x40u || (low == 0x40u && (base & 1u))) ? 1u : 0u;
  if (base > 0x7eu) base = 0x7eu;
  return (u8)(((h >> 8) & 0x80u) | base);
}

// accumulate 4 fp8 (one u32) into a[0..3]; values scaled 1/256 (hoisted)
__device__ __forceinline__ void acc4(u32 w, float* a) {
#pragma unroll
  for (int i = 0; i < 4; i++) {
    u32 bb = (w >> (8 * i)) & 0xffu;
    a[i] += h16f(((bb & 0x80u) << 8) | ((bb & 0x7fu) << 7));
  }
}
__device__ __forceinline__ void accrow(uint4 r0, uint4 r1, float* acc) {
  acc4(r0.x, acc + 0);  acc4(r0.y, acc + 4);
  acc4(r0.z, acc + 8);  acc4(r0.w, acc + 12);
  acc4(r1.x, acc + 16); acc4(r1.y, acc + 20);
  acc4(r1.z, acc + 24); acc4(r1.w, acc + 28);
}

// ---------------- bucketed CSR build ----------------
__global__ __launch_bounds__(256) void k_bzero(int* __restrict__ bcnt) {
  int g = blockIdx.x * 256 + threadIdx.x;
  if (g < NBK) bcnt[g] = 0;
}

__global__ __launch_bounds__(256) void k_bhist(const int* __restrict__ ei,
                                               int* __restrict__ bcnt) {
  __shared__ int h[NBK];
  int t = threadIdx.x;
  for (int i = t; i < NBK; i += 256) h[i] = 0;
  __syncthreads();
  for (int g = blockIdx.x * 256 + t; g < NE; g += gridDim.x * 256)
    atomicAdd(&h[ei[NE + g] >> 7], 1);
  __syncthreads();
  for (int i = t; i < NBK; i += 256)
    if (h[i]) atomicAdd(&bcnt[i], h[i]);
}

__global__ __launch_bounds__(1024) void k_bscan(const int* __restrict__ bcnt,
                                                int* __restrict__ boff,
                                                int* __restrict__ bcur) {
  __shared__ int sm[1024];
  int t = threadIdx.x;
  int v = (t < NBK) ? bcnt[t] : 0;
  sm[t] = v;
  __syncthreads();
  for (int d = 1; d < 1024; d <<= 1) {
    int x = (t >= d) ? sm[t - d] : 0;
    __syncthreads();
    sm[t] += x;
    __syncthreads();
  }
  if (t < NBK) {
    int excl = sm[t] - v;
    boff[t] = excl;
    bcur[t] = excl;
  }
  if (t == 0) boff[NBK] = NE;
}

__global__ __launch_bounds__(256) void k_bscatter(const int* __restrict__ ei,
                                                  int* __restrict__ bcur,
                                                  int* __restrict__ ppack) {
  __shared__ int lexcl[NBK];
  __shared__ int lcur[NBK];
  __shared__ int gdelta[NBK];
  __shared__ int lbuf[SCHUNK];
  __shared__ unsigned short lbkt[SCHUNK];
  __shared__ int sm[256];
  int t = threadIdx.x;
  int e0 = blockIdx.x * SCHUNK;
  for (int i = t; i < NBK; i += 256) lexcl[i] = 0;
  __syncthreads();
  for (int i = t; i < SCHUNK; i += 256)
    atomicAdd(&lexcl[((u32)ei[NE + e0 + i]) >> 7], 1);
  __syncthreads();
  int b0 = t * 4;
  int c0 = 0, c1 = 0, c2 = 0, c3 = 0;
  if (b0 < NBK) {
    c0 = lexcl[b0];
    c1 = (b0 + 1 < NBK) ? lexcl[b0 + 1] : 0;
    c2 = (b0 + 2 < NBK) ? lexcl[b0 + 2] : 0;
    c3 = (b0 + 3 < NBK) ? lexcl[b0 + 3] : 0;
  }
  int tot = c0 + c1 + c2 + c3;
  sm[t] = tot;
  __syncthreads();
  for (int d = 1; d < 256; d <<= 1) {
    int x = (t >= d) ? sm[t - d] : 0;
    __syncthreads();
    sm[t] += x;
    __syncthreads();
  }
  int base = sm[t] - tot;
  if (b0 < NBK) {
    int cnts[4] = {c0, c1, c2, c3};
    int e = base;
#pragma unroll
    for (int j = 0; j < 4; j++) {
      int b = b0 + j;
      if (b < NBK) {
        int c = cnts[j];
        lexcl[b] = e;
        lcur[b] = e;
        if (c > 0) gdelta[b] = atomicAdd(&bcur[b], c) - e;
        e += c;
      }
    }
  }
  __syncthreads();
  for (int i = t; i < SCHUNK; i += 256) {
    int s = ei[e0 + i];
    u32 d = (u32)ei[NE + e0 + i];
    int b = d >> 7;
    int p = atomicAdd(&lcur[b], 1);
    lbuf[p] = (int)(((d & 127u) << 20) | (u32)s);
    lbkt[p] = (unsigned short)b;
  }
  __syncthreads();
  for (int i = t; i < SCHUNK; i += 256) {
    int b = lbkt[i];
    ppack[gdelta[b] + i] = lbuf[i];
  }
}

__global__ __launch_bounds__(256) void k_bfinal(const int* __restrict__ boff,
                                                const int* __restrict__ ppack,
                                                int* __restrict__ off,
                                                int* __restrict__ srcs) {
  __shared__ int ncnt[128];
  __shared__ int nincl[128];
  int b = blockIdx.x, t = threadIdx.x;
  int e0 = boff[b], e1 = boff[b + 1];
  if (t < 128) ncnt[t] = 0;
  __syncthreads();
  for (int i = e0 + t; i < e1; i += 256) atomicAdd(&ncnt[((u32)ppack[i]) >> 20], 1);
  __syncthreads();
  if (t < 128) nincl[t] = ncnt[t];
  __syncthreads();
  for (int d = 1; d < 128; d <<= 1) {
    int x = 0;
    if (t < 128 && t >= d) x = nincl[t - d];
    __syncthreads();
    if (t < 128) nincl[t] += x;
    __syncthreads();
  }
  int node0 = b * 128;
  if (t < 128) {
    int excl = nincl[t] - ncnt[t];
    int node = node0 + t;
    if (node < NN) off[node] = e0 + excl;
    ncnt[t] = excl;
  }
  if (b == 0 && t == 0) off[NN] = NE;
  __syncthreads();
  for (int i = e0 + t; i < e1; i += 256) {
    u32 v = (u32)ppack[i];
    int dl = v >> 20;
    int pos = atomicAdd(&ncnt[dl], 1);
    srcs[e0 + pos] = (int)(v & 0xFFFFF);
  }
}

// ---------------- drug branch ----------------
// conflict-free conv (validated R14): e staged in 2 chunks of 50 channels;
// window read as 5 x float2.
__global__ __launch_bounds__(256) void k_conv(
    const int* __restrict__ xd, const float* __restrict__ emb,
    const float* __restrict__ convw, const float* __restrict__ convb,
    float* __restrict__ C) {
  __shared__ float e_s[50 * 132 + 16];
  __shared__ float w_s[4 * 800];
  __shared__ int xd_s[100];
  int t = threadIdx.x;
  int b = blockIdx.x >> 3;
  int og = (blockIdx.x & 7) << 2;
  if (t < 100) xd_s[t] = xd[b * 100 + t];
  for (int i = t; i < 3200; i += 256) w_s[i] = convw[og * 800 + i];
  int ol = t >> 6;
  int ht = t & 63;
  int h0 = ht * 2;
  float a0 = 0.f, a1 = 0.f;
  const float4* wv = (const float4*)&w_s[ol * 800];
  for (int c = 0; c < 2; c++) {
    __syncthreads();
    for (int idx = t; idx < 6400; idx += 256) {
      int ch = idx >> 7, pos = idx & 127;
      e_s[ch * 132 + pos] = emb[xd_s[c * 50 + ch] * 128 + pos];
    }
    __syncthreads();
    for (int i = 0; i < 50; i++) {
      const float2* ep2 = (const float2*)&e_s[i * 132 + h0];
      float2 v0 = ep2[0], v1 = ep2[1], v2 = ep2[2], v3 = ep2[3], v4 = ep2[4];
      int ci = c * 50 + i;
      float4 wa = wv[ci * 2], wb = wv[ci * 2 + 1];
      a0 += v0.x * wa.x + v0.y * wa.y + v1.x * wa.z + v1.y * wa.w +
            v2.x * wb.x + v2.y * wb.y + v3.x * wb.z + v3.y * wb.w;
      a1 += v0.y * wa.x + v1.x * wa.y + v1.y * wa.z + v2.x * wa.w +
            v2.y * wb.x + v3.x * wb.y + v3.y * wb.z + v4.x * wb.w;
    }
  }
  int o = og + ol;
  float bb = convb[o];
  float* cp = &C[b * 3872 + o * 121];
  if (h0 < 121) cp[h0] = a0 + bb;
  if (h0 + 1 < 121) cp[h0 + 1] = a1 + bb;
}

__global__ __launch_bounds__(256) void k_fcd(
    const float* __restrict__ C, const float* __restrict__ fcdw,
    const float* __restrict__ fcdb, float* __restrict__ XJ) {
  __shared__ float c_s[3872];
  __shared__ float red[128];
  int t = threadIdx.x, b = blockIdx.x;
  for (int i = t; i < 3872; i += 256) c_s[i] = C[b * 3872 + i];
  __syncthreads();
  int j = t & 127, half = t >> 7;
  float acc = 0.f;
  int k0 = half * 1936;
  for (int k = k0; k < k0 + 1936; k++) acc += c_s[k] * fcdw[k * 128 + j];
  if (half) red[j] = acc;
  __syncthreads();
  if (!half) XJ[b * 256 + j] = acc + red[j] + fcdb[j];
}

// ---------------- protein branch ----------------
__global__ __launch_bounds__(256) void k_z1(
    const float* __restrict__ xt, const float* __restrict__ w1,
    u8* __restrict__ Z, float* __restrict__ pool) {
  __shared__ float xs[256 * FTD];
  __shared__ float w1s[FTD * DIM];
  int t = threadIdx.x;
  int base = blockIdx.x * 256;
  int g = base + t;
  if (g < NB * DIM) pool[g] = 0.f;
  for (int i = t; i < FTD * DIM; i += 256) w1s[i] = w1[i];
  int cnt = min(256, NN - base);
  for (int i = t; i < cnt * FTD; i += 256) xs[i] = xt[base * FTD + i];
  __syncthreads();
  int n = base + t;
  if (n < NN) {
    float acc[DIM];
#pragma unroll
    for (int j = 0; j < DIM; j++) acc[j] = 0.f;
    for (int k = 0; k < FTD; k++) {
      float xk = xs[t * FTD + k];
#pragma unroll
      for (int j = 0; j < DIM; j++) acc[j] += xk * w1s[k * DIM + j];
    }
    u8* zp = &Z[n * DIM];
#pragma unroll
    for (int j = 0; j < DIM; j++) zp[j] = f8enc(acc[j]);
  }
}

// Fused GIN layer: 128 nodes/block, NODE-PER-THREAD gather (epilogue once
// per node), 4 edges per iter via ONE int4 srcs load -> 8 independent uint4
// row loads in flight. bridge: u32-packed f16, stride 17, barrier.
// P2: 4 groups x 32 nodes, shfl-based MLP (validated logic).
template <int HAS_NEXT, int DO_POOL>
__global__ __launch_bounds__(128) void k_gin(
    const int* __restrict__ off, const int* __restrict__ srcs,
    const u8* __restrict__ Zin, const float* __restrict__ b1,
    const float* __restrict__ w2, const float* __restrict__ b2,
    const float* __restrict__ bng, const float* __restrict__ bnb,
    const float* __restrict__ bnrm, const float* __restrict__ bnrv,
    const float* __restrict__ w1n, u8* __restrict__ Zout,
    float* __restrict__ pool, const int* __restrict__ batch) {
  __shared__ float w2s[DIM * DIM];
  __shared__ float w1ns[DIM * DIM];
  __shared__ u32 aggs[128 * 17];
  int t = threadIdx.x;
  for (int i = t; i < DIM * DIM; i += 128) {
    w2s[i] = w2[i];
    if (HAS_NEXT) w1ns[i] = w1n[i];
  }
  int n = blockIdx.x * 128 + t;
  if (n < NN) {
    float acc[DIM];
#pragma unroll
    for (int i = 0; i < DIM; i++) acc[i] = 0.f;
    const uint4* zr = (const uint4*)(Zin + n * DIM);
    accrow(zr[0], zr[1], acc);
    int beg = off[n], end = off[n + 1];
    int j = beg;
    for (; j < end && (j & 3); j++) {
      const uint4* r = (const uint4*)(Zin + srcs[j] * DIM);
      uint4 r0 = r[0], r1 = r[1];
      accrow(r0, r1, acc);
    }
    for (; j + 4 <= end; j += 4) {
      int4 s4 = *(const int4*)&srcs[j];
      const uint4* rx = (const uint4*)(Zin + s4.x * DIM);
      const uint4* ry = (const uint4*)(Zin + s4.y * DIM);
      const uint4* rz = (const uint4*)(Zin + s4.z * DIM);
      const uint4* rw = (const uint4*)(Zin + s4.w * DIM);
      uint4 x0 = rx[0], x1 = rx[1];
      uint4 y0 = ry[0], y1 = ry[1];
      uint4 z0 = rz[0], z1 = rz[1];
      uint4 w0 = rw[0], w1 = rw[1];
      accrow(x0, x1, acc);
      accrow(y0, y1, acc);
      accrow(z0, z1, acc);
      accrow(w0, w1, acc);
    }
    for (; j < end; j++) {
      const uint4* r = (const uint4*)(Zin + srcs[j] * DIM);
      uint4 r0 = r[0], r1 = r[1];
      accrow(r0, r1, acc);
    }
#pragma unroll
    for (int q = 0; q < 16; q++)
      aggs[t * 17 + q] = pk2(acc[2 * q], acc[2 * q + 1]);
  }
  __syncthreads();
  // ---- P2: MLP (feature-parallel, shfl-based) ----
  int g = t >> 5, f = t & 31;
  float b1f = b1[f], b2f = b2[f];
  float sc = bng[f] * rsqrtf(bnrv[f] + 1e-5f);
  float sh = bnb[f] - bnrm[f] * sc;
  int w = f >> 1, hi = f & 1;
#pragma unroll 1
  for (int mm = 0; mm < 32; mm++) {
    int lm = g * 32 + mm;
    int node = blockIdx.x * 128 + lm;
    if (node >= NN) break;
    u32 u = aggs[lm * 17 + w];
    float agg = h16f(hi ? (u >> 16) : (u & 0xffffu)) * 256.0f;
    float hid = fmaxf(agg + b1f, 0.f);
    float o = b2f;
#pragma unroll
    for (int k = 0; k < DIM; k++) o += __shfl(hid, k, 32) * w2s[k * DIM + f];
    float hn = fmaxf(o, 0.f) * sc + sh;
    if (HAS_NEXT) {
      float z = 0.f;
#pragma unroll
      for (int k = 0; k < DIM; k++) z += __shfl(hn, k, 32) * w1ns[k * DIM + f];
      Zout[node * DIM + f] = f8enc(z);
    }
    if (DO_POOL) atomicAdd(&pool[batch[node] * DIM + f], hn);
  }
}

__global__ __launch_bounds__(128) void k_fct(
    const float* __restrict__ pool, const float* __restrict__ fctw,
    const float* __restrict__ fctb, float* __restrict__ XJ) {
  __shared__ float p_s[DIM];
  int t = threadIdx.x, b = blockIdx.x;
  if (t < DIM) p_s[t] = pool[b * DIM + t];
  __syncthreads();
  float acc = fctb[t];
  for (int k = 0; k < DIM; k++) acc += p_s[k] * fctw[k * 128 + t];
  XJ[b * 256 + 128 + t] = fmaxf(acc, 0.f);
}

__global__ __launch_bounds__(256) void k_c1(
    const float* __restrict__ XJ, const float* __restrict__ w,
    const float* __restrict__ bias, float* __restrict__ H1) {
  __shared__ float xs[256];
  int t = threadIdx.x, b = blockIdx.y;
  xs[t] = XJ[b * 256 + t];
  __syncthreads();
  int j = blockIdx.x * 256 + t;
  float acc = bias[j];
  for (int k = 0; k < 256; k++) acc += xs[k] * w[k * 1024 + j];
  H1[b * 1024 + j] = fmaxf(acc, 0.f);
}

__global__ __launch_bounds__(256) void k_c2(
    const float* __restrict__ H1, const float* __restrict__ w,
    const float* __restrict__ bias, float* __restrict__ H2) {
  __shared__ float hs[1024];
  int t = threadIdx.x, b = blockIdx.x;
  for (int i = t; i < 1024; i += 256) hs[i] = H1[b * 1024 + i];
  __syncthreads();
  float acc = bias[t];
  for (int k = 0; k < 1024; k++) acc += hs[k] * w[k * 256 + t];
  H2[b * 256 + t] = fmaxf(acc, 0.f);
}

__global__ __launch_bounds__(64) void k_c3(
    const float* __restrict__ H2, const float* __restrict__ w,
    const float* __restrict__ bias, const float* __restrict__ y,
    float* __restrict__ out) {
  int b = blockIdx.x * 64 + threadIdx.x;
  float acc = bias[0];
  for (int k = 0; k < 256; k++) acc += H2[b * 256 + k] * w[k];
  out[b] = acc;
  out[NB + b] = y[b];
}

extern "C" void kernel_launch(void* const* d_in, const int* in_sizes, int n_in,
                              void* d_out, int out_size, void* d_ws,
                              size_t ws_size, hipStream_t stream) {
  const int* xd = (const int*)d_in[0];
  const float* xt = (const float*)d_in[1];
  const int* ei = (const int*)d_in[2];
  const int* batch = (const int*)d_in[3];
  const float* y = (const float*)d_in[4];
  const float* emb = (const float*)d_in[5];
  const float* convw = (const float*)d_in[6];
  const float* convb = (const float*)d_in[7];
  const float* fcdw = (const float*)d_in[8];
  const float* fcdb = (const float*)d_in[9];
  const float* g1w1 = (const float*)d_in[10];
  const float* g1b1 = (const float*)d_in[11];
  const float* g1w2 = (const float*)d_in[12];
  const float* g1b2 = (const float*)d_in[13];
  const float* gw1 = (const float*)d_in[14];
  const float* gb1 = (const float*)d_in[15];
  const float* gw2 = (const float*)d_in[16];
  const float* gb2 = (const float*)d_in[17];
  const float* bng = (const float*)d_in[18];
  const float* bnb = (const float*)d_in[19];
  const float* bnrm = (const float*)d_in[20];
  const float* bnrv = (const float*)d_in[21];
  const float* fctw = (const float*)d_in[22];
  const float* fctb = (const float*)d_in[23];
  const float* c1w = (const float*)d_in[24];
  const float* c1b = (const float*)d_in[25];
  const float* c2w = (const float*)d_in[26];
  const float* c2b = (const float*)d_in[27];
  const float* c3w = (const float*)d_in[28];
  const float* c3b = (const float*)d_in[29];
  float* out = (float*)d_out;

  u8* Z0 = (u8*)d_ws;                        // NN*32 fp8
  u8* Z1 = Z0 + (size_t)NN * DIM;            // NN*32 fp8
  int* srcs = (int*)(Z1 + (size_t)NN * DIM); // NE int
  int* off = srcs + NE;                      // NN+1
  int* bcnt = off + NN + 1;                  // NBK
  int* boff = bcnt + NBK;                    // NBK+1
  int* bcur = boff + NBK + 1;                // NBK
  // union region: ppack (CSR build) aliases drug/classifier temps
  int* ppack = bcur + NBK;                   // NE int
  float* C = (float*)ppack;                  // 256*3872
  float* XJ = C + (size_t)NB * 3872;         // 256*256
  float* H1 = XJ + NB * 256;                 // 256*1024
  float* H2 = H1 + NB * 1024;                // 256*256
  float* POOL = H2 + NB * 256;               // 256*32

  int nblk = (NN + 255) / 256;
  int gblk = (NN + 127) / 128;  // 782

  // CSR build (edge list is layer-invariant)
  k_bzero<<<(NBK + 255) / 256, 256, 0, stream>>>(bcnt);
  k_bhist<<<512, 256, 0, stream>>>(ei, bcnt);
  k_bscan<<<1, 1024, 0, stream>>>(bcnt, boff, bcur);
  k_bscatter<<<NE / SCHUNK, 256, 0, stream>>>(ei, bcur, ppack);
  k_bfinal<<<NBK, 256, 0, stream>>>(boff, ppack, off, srcs);

  // drug branch (reuses ppack region — stream-ordered, ppack dead)
  k_conv<<<NB * 8, 256, 0, stream>>>(xd, emb, convw, convb, C);
  k_fcd<<<NB, 256, 0, stream>>>(C, fcdw, fcdb, XJ);

  // protein branch
  k_z1<<<nblk, 256, 0, stream>>>(xt, g1w1, Z0, POOL);
  u8* zin = Z0;
  u8* zout = Z1;
  for (int i = 0; i < 5; i++) {
    const float *b1, *w2, *b2;
    if (i == 0) { b1 = g1b1; w2 = g1w2; b2 = g1b2; }
    else {
      b1 = gb1 + (i - 1) * DIM;
      w2 = gw2 + (i - 1) * DIM * DIM;
      b2 = gb2 + (i - 1) * DIM;
    }
    const float* w1n = gw1 + i * DIM * DIM;  // only read when i<4
    if (i < 4)
      k_gin<1, 0><<<gblk, 128, 0, stream>>>(
          off, srcs, zin, b1, w2, b2, bng + i * DIM, bnb + i * DIM,
          bnrm + i * DIM, bnrv + i * DIM, w1n, zout, POOL, batch);
    else
      k_gin<0, 1><<<gblk, 128, 0, stream>>>(
          off, srcs, zin, b1, w2, b2, bng + i * DIM, bnb + i * DIM,
          bnrm + i * DIM, bnrv + i * DIM, w1n, zout, POOL, batch);
    u8* tmp = zin; zin = zout; zout = tmp;
  }
  k_fct<<<NB, 128, 0, stream>>>(POOL, fctw, fctb, XJ);
  k_c1<<<dim3(4, NB), 256, 0, stream>>>(XJ, c1w, c1b, H1);
  k_c2<<<NB, 256, 0, stream>>>(H1, c2w, c2b, H2);
  k_c3<<<4, 64, 0, stream>>>(H2, c3w, c3b, y, out);
}

// Round 16
// 658.414 us; speedup vs baseline: 1.2868x; 1.2868x over previous
//
#include <hip/hip_runtime.h>

typedef unsigned int u32;
typedef unsigned char u8;

#define NN 100000
#define NE 3200000
#define NB 256
#define FTD 41
#define DIM 32
#define NBK 782      // ceil(NN/128)
#define SCHUNK 8000  // edges per k_bscatter block; 400*8000 == NE

typedef __fp16 fp16x2 __attribute__((ext_vector_type(2)));
typedef float f32x2 __attribute__((ext_vector_type(2)));

#if __has_builtin(__builtin_amdgcn_cvt_pk_f32_fp8)
#define HAS_FP8CVT 1
#endif

__device__ __forceinline__ float h16f(u32 bits) {
  union { unsigned short s; _Float16 h; } c;
  c.s = (unsigned short)bits;
  return (float)c.h;
}
__device__ __forceinline__ u32 pk2(float a, float b) {
  union { fp16x2 h; u32 u; } c;
  c.h = __builtin_amdgcn_cvt_pkrtz(a, b);
  return c.u;
}

// fp8 e4m3fn encode (software, OCP-compatible; RNE via f16 path)
__device__ __forceinline__ u8 f8enc(float v) {
  union { _Float16 h; unsigned short u; } cv;
  cv.h = (_Float16)(v * 0.00390625f);  // v / 256
  u32 h = cv.u;
  u32 mag = h & 0x7fffu;
  u32 base = mag >> 7;
  u32 low = mag & 0x7fu;
  base += (low > 0x40u || (low == 0x40u && (base & 1u))) ? 1u : 0u;
  if (base > 0x7eu) base = 0x7eu;
  return (u8)(((h >> 8) & 0x80u) | base);
}

// accumulate 4 fp8 (one u32) into a[0..3] as TRUE e4m3 values.
// HW path: v_cvt_pk_f32_fp8 (2 features/instr). SW fallback identical values.
__device__ __forceinline__ void acc4(u32 w, float* a) {
#ifdef HAS_FP8CVT
  f32x2 lo = __builtin_amdgcn_cvt_pk_f32_fp8((int)w, false);  // bytes 0,1
  f32x2 hi = __builtin_amdgcn_cvt_pk_f32_fp8((int)w, true);   // bytes 2,3
  a[0] += lo.x; a[1] += lo.y; a[2] += hi.x; a[3] += hi.y;
#else
#pragma unroll
  for (int i = 0; i < 4; i++) {
    u32 bb = (w >> (8 * i)) & 0xffu;
    a[i] += h16f(((bb & 0x80u) << 8) | ((bb & 0x7fu) << 7)) * 256.0f;
  }
#endif
}
__device__ __forceinline__ void accrow(uint4 r0, uint4 r1, float* acc) {
  acc4(r0.x, acc + 0);  acc4(r0.y, acc + 4);
  acc4(r0.z, acc + 8);  acc4(r0.w, acc + 12);
  acc4(r1.x, acc + 16); acc4(r1.y, acc + 20);
  acc4(r1.z, acc + 24); acc4(r1.w, acc + 28);
}

// ---------------- bucketed CSR build ----------------
__global__ __launch_bounds__(256) void k_bzero(int* __restrict__ bcnt) {
  int g = blockIdx.x * 256 + threadIdx.x;
  if (g < NBK) bcnt[g] = 0;
}

__global__ __launch_bounds__(256) void k_bhist(const int* __restrict__ ei,
                                               int* __restrict__ bcnt) {
  __shared__ int h[NBK];
  int t = threadIdx.x;
  for (int i = t; i < NBK; i += 256) h[i] = 0;
  __syncthreads();
  for (int g = blockIdx.x * 256 + t; g < NE; g += gridDim.x * 256)
    atomicAdd(&h[ei[NE + g] >> 7], 1);
  __syncthreads();
  for (int i = t; i < NBK; i += 256)
    if (h[i]) atomicAdd(&bcnt[i], h[i]);
}

__global__ __launch_bounds__(1024) void k_bscan(const int* __restrict__ bcnt,
                                                int* __restrict__ boff,
                                                int* __restrict__ bcur) {
  __shared__ int sm[1024];
  int t = threadIdx.x;
  int v = (t < NBK) ? bcnt[t] : 0;
  sm[t] = v;
  __syncthreads();
  for (int d = 1; d < 1024; d <<= 1) {
    int x = (t >= d) ? sm[t - d] : 0;
    __syncthreads();
    sm[t] += x;
    __syncthreads();
  }
  if (t < NBK) {
    int excl = sm[t] - v;
    boff[t] = excl;
    bcur[t] = excl;
  }
  if (t == 0) boff[NBK] = NE;
}

__global__ __launch_bounds__(256) void k_bscatter(const int* __restrict__ ei,
                                                  int* __restrict__ bcur,
                                                  int* __restrict__ ppack) {
  __shared__ int lexcl[NBK];
  __shared__ int lcur[NBK];
  __shared__ int gdelta[NBK];
  __shared__ int lbuf[SCHUNK];
  __shared__ unsigned short lbkt[SCHUNK];
  __shared__ int sm[256];
  int t = threadIdx.x;
  int e0 = blockIdx.x * SCHUNK;
  for (int i = t; i < NBK; i += 256) lexcl[i] = 0;
  __syncthreads();
  for (int i = t; i < SCHUNK; i += 256)
    atomicAdd(&lexcl[((u32)ei[NE + e0 + i]) >> 7], 1);
  __syncthreads();
  int b0 = t * 4;
  int c0 = 0, c1 = 0, c2 = 0, c3 = 0;
  if (b0 < NBK) {
    c0 = lexcl[b0];
    c1 = (b0 + 1 < NBK) ? lexcl[b0 + 1] : 0;
    c2 = (b0 + 2 < NBK) ? lexcl[b0 + 2] : 0;
    c3 = (b0 + 3 < NBK) ? lexcl[b0 + 3] : 0;
  }
  int tot = c0 + c1 + c2 + c3;
  sm[t] = tot;
  __syncthreads();
  for (int d = 1; d < 256; d <<= 1) {
    int x = (t >= d) ? sm[t - d] : 0;
    __syncthreads();
    sm[t] += x;
    __syncthreads();
  }
  int base = sm[t] - tot;
  if (b0 < NBK) {
    int cnts[4] = {c0, c1, c2, c3};
    int e = base;
#pragma unroll
    for (int j = 0; j < 4; j++) {
      int b = b0 + j;
      if (b < NBK) {
        int c = cnts[j];
        lexcl[b] = e;
        lcur[b] = e;
        if (c > 0) gdelta[b] = atomicAdd(&bcur[b], c) - e;
        e += c;
      }
    }
  }
  __syncthreads();
  for (int i = t; i < SCHUNK; i += 256) {
    int s = ei[e0 + i];
    u32 d = (u32)ei[NE + e0 + i];
    int b = d >> 7;
    int p = atomicAdd(&lcur[b], 1);
    lbuf[p] = (int)(((d & 127u) << 20) | (u32)s);
    lbkt[p] = (unsigned short)b;
  }
  __syncthreads();
  for (int i = t; i < SCHUNK; i += 256) {
    int b = lbkt[i];
    ppack[gdelta[b] + i] = lbuf[i];
  }
}

__global__ __launch_bounds__(256) void k_bfinal(const int* __restrict__ boff,
                                                const int* __restrict__ ppack,
                                                int* __restrict__ off,
                                                int* __restrict__ srcs) {
  __shared__ int ncnt[128];
  __shared__ int nincl[128];
  int b = blockIdx.x, t = threadIdx.x;
  int e0 = boff[b], e1 = boff[b + 1];
  if (t < 128) ncnt[t] = 0;
  __syncthreads();
  for (int i = e0 + t; i < e1; i += 256) atomicAdd(&ncnt[((u32)ppack[i]) >> 20], 1);
  __syncthreads();
  if (t < 128) nincl[t] = ncnt[t];
  __syncthreads();
  for (int d = 1; d < 128; d <<= 1) {
    int x = 0;
    if (t < 128 && t >= d) x = nincl[t - d];
    __syncthreads();
    if (t < 128) nincl[t] += x;
    __syncthreads();
  }
  int node0 = b * 128;
  if (t < 128) {
    int excl = nincl[t] - ncnt[t];
    int node = node0 + t;
    if (node < NN) off[node] = e0 + excl;
    ncnt[t] = excl;
  }
  if (b == 0 && t == 0) off[NN] = NE;
  __syncthreads();
  for (int i = e0 + t; i < e1; i += 256) {
    u32 v = (u32)ppack[i];
    int dl = v >> 20;
    int pos = atomicAdd(&ncnt[dl], 1);
    srcs[e0 + pos] = (int)(v & 0xFFFFF);
  }
}

// ---------------- drug branch ----------------
// conflict-free conv (validated R14): e staged in 2 chunks of 50 channels;
// window read as 5 x float2.
__global__ __launch_bounds__(256) void k_conv(
    const int* __restrict__ xd, const float* __restrict__ emb,
    const float* __restrict__ convw, const float* __restrict__ convb,
    float* __restrict__ C) {
  __shared__ float e_s[50 * 132 + 16];
  __shared__ float w_s[4 * 800];
  __shared__ int xd_s[100];
  int t = threadIdx.x;
  int b = blockIdx.x >> 3;
  int og = (blockIdx.x & 7) << 2;
  if (t < 100) xd_s[t] = xd[b * 100 + t];
  for (int i = t; i < 3200; i += 256) w_s[i] = convw[og * 800 + i];
  int ol = t >> 6;
  int ht = t & 63;
  int h0 = ht * 2;
  float a0 = 0.f, a1 = 0.f;
  const float4* wv = (const float4*)&w_s[ol * 800];
  for (int c = 0; c < 2; c++) {
    __syncthreads();
    for (int idx = t; idx < 6400; idx += 256) {
      int ch = idx >> 7, pos = idx & 127;
      e_s[ch * 132 + pos] = emb[xd_s[c * 50 + ch] * 128 + pos];
    }
    __syncthreads();
    for (int i = 0; i < 50; i++) {
      const float2* ep2 = (const float2*)&e_s[i * 132 + h0];
      float2 v0 = ep2[0], v1 = ep2[1], v2 = ep2[2], v3 = ep2[3], v4 = ep2[4];
      int ci = c * 50 + i;
      float4 wa = wv[ci * 2], wb = wv[ci * 2 + 1];
      a0 += v0.x * wa.x + v0.y * wa.y + v1.x * wa.z + v1.y * wa.w +
            v2.x * wb.x + v2.y * wb.y + v3.x * wb.z + v3.y * wb.w;
      a1 += v0.y * wa.x + v1.x * wa.y + v1.y * wa.z + v2.x * wa.w +
            v2.y * wb.x + v3.x * wb.y + v3.y * wb.z + v4.x * wb.w;
    }
  }
  int o = og + ol;
  float bb = convb[o];
  float* cp = &C[b * 3872 + o * 121];
  if (h0 < 121) cp[h0] = a0 + bb;
  if (h0 + 1 < 121) cp[h0 + 1] = a1 + bb;
}

__global__ __launch_bounds__(256) void k_fcd(
    const float* __restrict__ C, const float* __restrict__ fcdw,
    const float* __restrict__ fcdb, float* __restrict__ XJ) {
  __shared__ float c_s[3872];
  __shared__ float red[128];
  int t = threadIdx.x, b = blockIdx.x;
  for (int i = t; i < 3872; i += 256) c_s[i] = C[b * 3872 + i];
  __syncthreads();
  int j = t & 127, half = t >> 7;
  float acc = 0.f;
  int k0 = half * 1936;
  for (int k = k0; k < k0 + 1936; k++) acc += c_s[k] * fcdw[k * 128 + j];
  if (half) red[j] = acc;
  __syncthreads();
  if (!half) XJ[b * 256 + j] = acc + red[j] + fcdb[j];
}

// ---------------- protein branch ----------------
__global__ __launch_bounds__(256) void k_z1(
    const float* __restrict__ xt, const float* __restrict__ w1,
    u8* __restrict__ Z, float* __restrict__ pool) {
  __shared__ float xs[256 * FTD];
  __shared__ float w1s[FTD * DIM];
  int t = threadIdx.x;
  int base = blockIdx.x * 256;
  int g = base + t;
  if (g < NB * DIM) pool[g] = 0.f;
  for (int i = t; i < FTD * DIM; i += 256) w1s[i] = w1[i];
  int cnt = min(256, NN - base);
  for (int i = t; i < cnt * FTD; i += 256) xs[i] = xt[base * FTD + i];
  __syncthreads();
  int n = base + t;
  if (n < NN) {
    float acc[DIM];
#pragma unroll
    for (int j = 0; j < DIM; j++) acc[j] = 0.f;
    for (int k = 0; k < FTD; k++) {
      float xk = xs[t * FTD + k];
#pragma unroll
      for (int j = 0; j < DIM; j++) acc[j] += xk * w1s[k * DIM + j];
    }
    u8* zp = &Z[n * DIM];
#pragma unroll
    for (int j = 0; j < DIM; j++) zp[j] = f8enc(acc[j]);
  }
}

// Fused GIN layer (R14-validated structure): 32 nodes/block, 8 threads/node
// edge-split (grid 3125). Only change vs R14: HW fp8 decode (true values,
// no x256 rescale).
template <int HAS_NEXT, int DO_POOL>
__global__ __launch_bounds__(256) void k_gin(
    const int* __restrict__ off, const int* __restrict__ srcs,
    const u8* __restrict__ Zin, const float* __restrict__ b1,
    const float* __restrict__ w2, const float* __restrict__ b2,
    const float* __restrict__ bng, const float* __restrict__ bnb,
    const float* __restrict__ bnrm, const float* __restrict__ bnrv,
    const float* __restrict__ w1n, u8* __restrict__ Zout,
    float* __restrict__ pool, const int* __restrict__ batch) {
  __shared__ float w2s[DIM * DIM];
  __shared__ float w1ns[DIM * DIM];
  __shared__ u32 aggs[256 * 17];  // packed f16 pair partial sums (true values)
  int t = threadIdx.x;
  for (int i = t; i < DIM * DIM; i += 256) {
    w2s[i] = w2[i];
    if (HAS_NEXT) w1ns[i] = w1n[i];
  }
  // ---- P1: gather (8-way split per node) ----
  int m = t >> 3, p = t & 7;
  int n = blockIdx.x * 32 + m;
  {
    float acc[DIM];
#pragma unroll
    for (int i = 0; i < DIM; i++) acc[i] = 0.f;
    int beg = off[n], end = off[n + 1];
    if (p == 0) {
      const uint4* zr = (const uint4*)(Zin + n * DIM);
      uint4 r0 = zr[0], r1 = zr[1];
      accrow(r0, r1, acc);
    }
    int j = beg + p;
    for (; j + 8 < end; j += 16) {
      int sA = srcs[j], sB = srcs[j + 8];
      const uint4* ra = (const uint4*)(Zin + sA * DIM);
      const uint4* rb = (const uint4*)(Zin + sB * DIM);
      uint4 a0 = ra[0], a1 = ra[1];
      uint4 c0 = rb[0], c1 = rb[1];
      accrow(a0, a1, acc);
      accrow(c0, c1, acc);
    }
    if (j < end) {
      int sA = srcs[j];
      const uint4* ra = (const uint4*)(Zin + sA * DIM);
      uint4 a0 = ra[0], a1 = ra[1];
      accrow(a0, a1, acc);
    }
#pragma unroll
    for (int q = 0; q < 16; q++)
      aggs[t * 17 + q] = pk2(acc[2 * q], acc[2 * q + 1]);
  }
  __syncthreads();
  // ---- P2: MLP (feature-parallel, shfl-based) ----
  int g = t >> 5, f = t & 31;
  float b1f = b1[f], b2f = b2[f];
  float sc = bng[f] * rsqrtf(bnrv[f] + 1e-5f);
  float sh = bnb[f] - bnrm[f] * sc;
  int w = f >> 1, hi = f & 1;
#pragma unroll 1
  for (int mm = 0; mm < 4; mm++) {
    int lm = g * 4 + mm;
    int node = blockIdx.x * 32 + lm;
    int s8 = lm * 8;
    float agg = 0.f;
#pragma unroll
    for (int q = 0; q < 8; q++) {
      u32 u = aggs[(s8 + q) * 17 + w];
      agg += h16f(hi ? (u >> 16) : (u & 0xffffu));
    }
    float hid = fmaxf(agg + b1f, 0.f);
    float o = b2f;
#pragma unroll
    for (int k = 0; k < DIM; k++) o += __shfl(hid, k, 32) * w2s[k * DIM + f];
    float hn = fmaxf(o, 0.f) * sc + sh;
    if (HAS_NEXT) {
      float z = 0.f;
#pragma unroll
      for (int k = 0; k < DIM; k++) z += __shfl(hn, k, 32) * w1ns[k * DIM + f];
      Zout[node * DIM + f] = f8enc(z);
    }
    if (DO_POOL) atomicAdd(&pool[batch[node] * DIM + f], hn);
  }
}

__global__ __launch_bounds__(128) void k_fct(
    const float* __restrict__ pool, const float* __restrict__ fctw,
    const float* __restrict__ fctb, float* __restrict__ XJ) {
  __shared__ float p_s[DIM];
  int t = threadIdx.x, b = blockIdx.x;
  if (t < DIM) p_s[t] = pool[b * DIM + t];
  __syncthreads();
  float acc = fctb[t];
  for (int k = 0; k < DIM; k++) acc += p_s[k] * fctw[k * 128 + t];
  XJ[b * 256 + 128 + t] = fmaxf(acc, 0.f);
}

__global__ __launch_bounds__(256) void k_c1(
    const float* __restrict__ XJ, const float* __restrict__ w,
    const float* __restrict__ bias, float* __restrict__ H1) {
  __shared__ float xs[256];
  int t = threadIdx.x, b = blockIdx.y;
  xs[t] = XJ[b * 256 + t];
  __syncthreads();
  int j = blockIdx.x * 256 + t;
  float acc = bias[j];
  for (int k = 0; k < 256; k++) acc += xs[k] * w[k * 1024 + j];
  H1[b * 1024 + j] = fmaxf(acc, 0.f);
}

__global__ __launch_bounds__(256) void k_c2(
    const float* __restrict__ H1, const float* __restrict__ w,
    const float* __restrict__ bias, float* __restrict__ H2) {
  __shared__ float hs[1024];
  int t = threadIdx.x, b = blockIdx.x;
  for (int i = t; i < 1024; i += 256) hs[i] = H1[b * 1024 + i];
  __syncthreads();
  float acc = bias[t];
  for (int k = 0; k < 1024; k++) acc += hs[k] * w[k * 256 + t];
  H2[b * 256 + t] = fmaxf(acc, 0.f);
}

__global__ __launch_bounds__(64) void k_c3(
    const float* __restrict__ H2, const float* __restrict__ w,
    const float* __restrict__ bias, const float* __restrict__ y,
    float* __restrict__ out) {
  int b = blockIdx.x * 64 + threadIdx.x;
  float acc = bias[0];
  for (int k = 0; k < 256; k++) acc += H2[b * 256 + k] * w[k];
  out[b] = acc;
  out[NB + b] = y[b];
}

extern "C" void kernel_launch(void* const* d_in, const int* in_sizes, int n_in,
                              void* d_out, int out_size, void* d_ws,
                              size_t ws_size, hipStream_t stream) {
  const int* xd = (const int*)d_in[0];
  const float* xt = (const float*)d_in[1];
  const int* ei = (const int*)d_in[2];
  const int* batch = (const int*)d_in[3];
  const float* y = (const float*)d_in[4];
  const float* emb = (const float*)d_in[5];
  const float* convw = (const float*)d_in[6];
  const float* convb = (const float*)d_in[7];
  const float* fcdw = (const float*)d_in[8];
  const float* fcdb = (const float*)d_in[9];
  const float* g1w1 = (const float*)d_in[10];
  const float* g1b1 = (const float*)d_in[11];
  const float* g1w2 = (const float*)d_in[12];
  const float* g1b2 = (const float*)d_in[13];
  const float* gw1 = (const float*)d_in[14];
  const float* gb1 = (const float*)d_in[15];
  const float* gw2 = (const float*)d_in[16];
  const float* gb2 = (const float*)d_in[17];
  const float* bng = (const float*)d_in[18];
  const float* bnb = (const float*)d_in[19];
  const float* bnrm = (const float*)d_in[20];
  const float* bnrv = (const float*)d_in[21];
  const float* fctw = (const float*)d_in[22];
  const float* fctb = (const float*)d_in[23];
  const float* c1w = (const float*)d_in[24];
  const float* c1b = (const float*)d_in[25];
  const float* c2w = (const float*)d_in[26];
  const float* c2b = (const float*)d_in[27];
  const float* c3w = (const float*)d_in[28];
  const float* c3b = (const float*)d_in[29];
  float* out = (float*)d_out;

  u8* Z0 = (u8*)d_ws;                        // NN*32 fp8
  u8* Z1 = Z0 + (size_t)NN * DIM;            // NN*32 fp8
  int* srcs = (int*)(Z1 + (size_t)NN * DIM); // NE int
  int* off = srcs + NE;                      // NN+1
  int* bcnt = off + NN + 1;                  // NBK
  int* boff = bcnt + NBK;                    // NBK+1
  int* bcur = boff + NBK + 1;                // NBK
  // union region: ppack (CSR build) aliases drug/classifier temps
  int* ppack = bcur + NBK;                   // NE int
  float* C = (float*)ppack;                  // 256*3872
  float* XJ = C + (size_t)NB * 3872;         // 256*256
  float* H1 = XJ + NB * 256;                 // 256*1024
  float* H2 = H1 + NB * 1024;                // 256*256
  float* POOL = H2 + NB * 256;               // 256*32

  int nblk = (NN + 255) / 256;
  int gblk = NN / 32;  // 3125, exact

  // CSR build (edge list is layer-invariant)
  k_bzero<<<(NBK + 255) / 256, 256, 0, stream>>>(bcnt);
  k_bhist<<<512, 256, 0, stream>>>(ei, bcnt);
  k_bscan<<<1, 1024, 0, stream>>>(bcnt, boff, bcur);
  k_bscatter<<<NE / SCHUNK, 256, 0, stream>>>(ei, bcur, ppack);
  k_bfinal<<<NBK, 256, 0, stream>>>(boff, ppack, off, srcs);

  // drug branch (reuses ppack region — stream-ordered, ppack dead)
  k_conv<<<NB * 8, 256, 0, stream>>>(xd, emb, convw, convb, C);
  k_fcd<<<NB, 256, 0, stream>>>(C, fcdw, fcdb, XJ);

  // protein branch
  k_z1<<<nblk, 256, 0, stream>>>(xt, g1w1, Z0, POOL);
  u8* zin = Z0;
  u8* zout = Z1;
  for (int i = 0; i < 5; i++) {
    const float *b1, *w2, *b2;
    if (i == 0) { b1 = g1b1; w2 = g1w2; b2 = g1b2; }
    else {
      b1 = gb1 + (i - 1) * DIM;
      w2 = gw2 + (i - 1) * DIM * DIM;
      b2 = gb2 + (i - 1) * DIM;
    }
    const float* w1n = gw1 + i * DIM * DIM;  // only read when i<4
    if (i < 4)
      k_gin<1, 0><<<gblk, 256, 0, stream>>>(
          off, srcs, zin, b1, w2, b2, bng + i * DIM, bnb + i * DIM,
          bnrm + i * DIM, bnrv + i * DIM, w1n, zout, POOL, batch);
    else
      k_gin<0, 1><<<gblk, 256, 0, stream>>>(
          off, srcs, zin, b1, w2, b2, bng + i * DIM, bnb + i * DIM,
          bnrm + i * DIM, bnrv + i * DIM, w1n, zout, POOL, batch);
    u8* tmp = zin; zin = zout; zout = tmp;
  }
  k_fct<<<NB, 128, 0, stream>>>(POOL, fctw, fctb, XJ);
  k_c1<<<dim3(4, NB), 256, 0, stream>>>(XJ, c1w, c1b, H1);
  k_c2<<<NB, 256, 0, stream>>>(H1, c2w, c2b, H2);
  k_c3<<<4, 64, 0, stream>>>(H2, c3w, c3b, y, out);
}